// Round 4
// baseline (285.848 us; speedup 1.0000x reference)
//
#include <hip/hip_runtime.h>
#include <stdint.h>

// DetectPeaksTM: per row of nt=8192 fp32, x=|xcorr|, sliding max window K=301
// (pad 150), scores = x where x==windowmax else 0, top-2 (score, idx).
// Outputs concatenated: [nrows*2] f32 scores, then [nrows*2] indices written
// as float values (harness reads whole d_out as float32; idx<8192 exact).
//
// R4: R3 was LDS-pipe throughput bound (~280 DS ops/wave x 5.8 cyc x 96
// waves/CU ~ 65 us). This round slashes DS ops:
//  - tier1 reads m[il+1 .. il+9] CONSECUTIVELY from a zero-padded m[] (no
//    index clamps -> compiler merges into ds_read2/dwordx reads), value-mask.
//  - tier2 edge check moved off LDS: exact element-masked global float4
//    re-reads (L1/L2-warm, only ~28 survivors/row). m4[] gone (8 KB LDS +
//    8 ds_writes/it saved), tier3 gone (edge check is exact now).
//  - LDS: 9.7 KB -> ~1.2 KB.

#define NT 8192
#define RADIUS 150
#define NTHREADS 256
#define NSEG (NT / 32)
#define MPAD (NSEG + 16)

__global__ __launch_bounds__(256) void detect_peaks_kernel(
    const float* __restrict__ x, float* __restrict__ out, int nrows)
{
    const int row = blockIdx.x;
    const int tid = threadIdx.x;

    __shared__ float m[MPAD];                 // 32-seg maxes + zero pad
    __shared__ unsigned long long wred[8];

    const float* grow = x + (size_t)row * NT;
    const float4* g4 = (const float4*)grow;

    if (tid < MPAD - NSEG) m[NSEG + tid] = 0.0f;   // pad so tier1 never clamps

    // ---- P1: load + abs + segment maxes + candidate mask ----
    float4 vv[8];
#pragma unroll
    for (int it = 0; it < 8; ++it) vv[it] = g4[it * 256 + tid];

    unsigned int cmask = 0u;
#pragma unroll
    for (int it = 0; it < 8; ++it) {
        const float4 v = vv[it];
        const float ax = fabsf(v.x), ay = fabsf(v.y);
        const float az = fabsf(v.z), aw = fabsf(v.w);
        const float cm4 = fmaxf(fmaxf(ax, ay), fmaxf(az, aw));
        // lanes 8k..8k+7 (same c>>3) hold the 8 float4 chunks of one 32-seg
        float cm = fmaxf(cm4, __shfl_xor(cm4, 1));
        cm = fmaxf(cm, __shfl_xor(cm, 2));
        cm = fmaxf(cm, __shfl_xor(cm, 4));
        const int c = it * 256 + tid;
        if ((tid & 7) == 0) m[c >> 3] = cm;
        cmask |= (ax == cm ? 1u : 0u) << (it * 4 + 0);
        cmask |= (ay == cm ? 1u : 0u) << (it * 4 + 1);
        cmask |= (az == cm ? 1u : 0u) << (it * 4 + 2);
        cmask |= (aw == cm ? 1u : 0u) << (it * 4 + 3);
    }
    __syncthreads();

    // ---- P2: candidate verification ----
    unsigned long long k1 = 0ull, k2 = 0ull;
    unsigned int mask = cmask;

    while (__ballot(mask != 0u) != 0ull) {
        const bool active = (mask != 0u);
        int i = 0;
        if (active) { i = __builtin_ctz(mask); mask &= (mask - 1u); }
        const int t = ((i >> 2) << 10) + (tid << 2) + (i & 3);
        if (active) {
            const int l = max(t - RADIUS, 0);
            const int r = min(t + RADIUS, NT - 1);
            const int il = l >> 5, ir = r >> 5;
            const float val = m[t >> 5];      // candidate == its segment max
            // tier1: interior full segs [il+1, ir-1], len in [3,9].
            // Consecutive unclamped reads from padded m -> merged DS reads.
            const int len = ir - il - 1;
            const float* mp = &m[il + 1];
            float iv[9];
#pragma unroll
            for (int j = 0; j < 9; ++j) iv[j] = mp[j];
            float im = 0.0f;
#pragma unroll
            for (int j = 0; j < 9; ++j) im = fmaxf(im, (j < len) ? iv[j] : 0.0f);
            if (!(im > val)) {
                // tier2: exact edge check via global re-reads (L1/L2-warm).
                // Head [l, (il+1)*32): partial only in first block (end is
                // 4-aligned). Tail [ir*32, r]: e<=r mask covers everything.
                float em = 0.0f;
                const int hb0 = l >> 2;
                const int hbN = il * 8 + 8;   // exclusive block end (<=2017)
#pragma unroll
                for (int j = 0; j < 8; ++j) {
                    const int b = hb0 + j;
                    const float4 q = g4[b];
                    float bm;
                    if (j == 0) {
                        bm = (4 * b + 0 >= l) ? fabsf(q.x) : 0.0f;
                        bm = fmaxf(bm, (4 * b + 1 >= l) ? fabsf(q.y) : 0.0f);
                        bm = fmaxf(bm, (4 * b + 2 >= l) ? fabsf(q.z) : 0.0f);
                        bm = fmaxf(bm, fabsf(q.w));          // 4b+3>=l always
                    } else {
                        bm = fmaxf(fmaxf(fabsf(q.x), fabsf(q.y)),
                                   fmaxf(fabsf(q.z), fabsf(q.w)));
                    }
                    em = fmaxf(em, (b < hbN) ? bm : 0.0f);
                }
                const int tb0 = ir * 8;       // tb0+7 <= 2047, no clamp needed
#pragma unroll
                for (int j = 0; j < 8; ++j) {
                    const int b = tb0 + j;
                    const float4 q = g4[b];
                    float bm;
                    bm = (4 * b + 0 <= r) ? fabsf(q.x) : 0.0f;
                    bm = fmaxf(bm, (4 * b + 1 <= r) ? fabsf(q.y) : 0.0f);
                    bm = fmaxf(bm, (4 * b + 2 <= r) ? fabsf(q.z) : 0.0f);
                    bm = fmaxf(bm, (4 * b + 3 <= r) ? fabsf(q.w) : 0.0f);
                    em = fmaxf(em, bm);
                }
                if (!(em > val)) {
                    const unsigned long long key =
                        ((unsigned long long)__float_as_uint(val) << 32) |
                        (unsigned)(NT - 1 - t);
                    if (key > k1) { k2 = k1; k1 = key; }
                    else if (key > k2) { k2 = key; }
                }
            }
        }
    }

    // ---- P3: top-2 reduction (wave shuffle, then 4 waves via LDS) ----
#pragma unroll
    for (int off = 32; off >= 1; off >>= 1) {
        unsigned long long o1 = __shfl_down(k1, off);
        unsigned long long o2 = __shfl_down(k2, off);
        unsigned long long hi = (k1 > o1) ? k1 : o1;
        unsigned long long lo = (k1 > o1) ? o1 : k1;
        unsigned long long s2 = (k2 > o2) ? k2 : o2;
        k1 = hi;
        k2 = (lo > s2) ? lo : s2;
    }
    const int wave = tid >> 6;
    if ((tid & 63) == 0) { wred[wave * 2] = k1; wred[wave * 2 + 1] = k2; }
    __syncthreads();

    if (tid == 0) {
        unsigned long long a1 = wred[0], a2 = wred[1];
        for (int w = 1; w < 4; ++w) {
            unsigned long long o1 = wred[w * 2], o2 = wred[w * 2 + 1];
            unsigned long long hi = (a1 > o1) ? a1 : o1;
            unsigned long long lo = (a1 > o1) ? o1 : a1;
            unsigned long long s2 = (a2 > o2) ? a2 : o2;
            a1 = hi;
            a2 = (lo > s2) ? lo : s2;
        }
        float s1v, s2v; int i1, i2;
        if (a1 == 0ull) { s1v = 0.0f; i1 = 0; }
        else {
            s1v = __uint_as_float((unsigned)(a1 >> 32));
            i1 = (NT - 1) - (int)(a1 & 0xffffffffull);
        }
        if (a2 == 0ull) {   // <2 peaks: second entry is first zero-score slot
            s2v = 0.0f;
            i2 = (i1 == 0) ? 1 : 0;
        } else {
            s2v = __uint_as_float((unsigned)(a2 >> 32));
            i2 = (NT - 1) - (int)(a2 & 0xffffffffull);
        }
        out[row * 2 + 0] = s1v;
        out[row * 2 + 1] = s2v;
        float* oi = out + (size_t)nrows * 2;
        oi[row * 2 + 0] = (float)i1;
        oi[row * 2 + 1] = (float)i2;
    }
}

extern "C" void kernel_launch(void* const* d_in, const int* in_sizes, int n_in,
                              void* d_out, int out_size, void* d_ws, size_t ws_size,
                              hipStream_t stream) {
    const float* x = (const float*)d_in[0];
    // d_in[1] = nlag (unused by the reference)
    float* out = (float*)d_out;
    const int nrows = in_sizes[0] / NT;  // 32*3*64 = 6144
    detect_peaks_kernel<<<nrows, NTHREADS, 0, stream>>>(x, out, nrows);
}